// Round 4
// baseline (109.480 us; speedup 1.0000x reference)
//
#include <hip/hip_runtime.h>

// HEGN loss: L_reg + bidirectional chamfer(x, y).  B=8, N=M=4096.
#define BB 8
#define NN 4096
#define MC 256                    // reference points staged per chunk
#define NCHUNK (NN / MC)          // 16
#define KPT 16                    // query points per thread
#define TPB 64                    // one wave per block
#define PTS_PER_BLOCK (TPB * KPT) // 1024
#define NPTS (2 * BB * NN)        // 65536 (both directions)

// ws layout: partial[c][zb][p]  c in [0,16), zb in [0,16), p in [0,4096) -> 4 MB

typedef __attribute__((ext_vector_type(2))) float f2;

__device__ __forceinline__ f2 pk_fma(f2 a, f2 b, f2 c) {
  f2 d;
  asm("v_pk_fma_f32 %0, %1, %2, %3" : "=v"(d) : "v"(a), "v"(b), "v"(c));
  return d;
}

__global__ __launch_bounds__(TPB) void chamfer_partial(
    const float* __restrict__ X, const float* __restrict__ Y,
    float* __restrict__ partial, float* __restrict__ out) {
  // Pair-packed staging: lxy[jp]=(-2x0,-2x1,-2y0,-2y1), lzw[jp]=(-2z0,-2z1,|r0|^2,|r1|^2)
  __shared__ float4 lxy[MC / 2];
  __shared__ float4 lzw[MC / 2];
  const int tid = threadIdx.x;
  const int zb  = blockIdx.z;     // (dir<<3) | b
  const int b   = zb & (BB - 1);
  const int dir = zb >> 3;
  const float* pts  = dir ? (Y + b * NN * 3) : (X + b * NN * 3);
  const float* refs = dir ? (X + b * NN * 3) : (Y + b * NN * 3);
  const int c = blockIdx.y;

  // Zero the output once; stream order guarantees this lands before
  // chamfer_reduce's atomics (no inter-block ordering needed).
  if (blockIdx.x == 0 && blockIdx.y == 0 && blockIdx.z == 0 && tid == 0)
    out[0] = 0.0f;

  for (int i = tid; i < MC / 2; i += TPB) {
    const int j = c * MC + 2 * i;
    const float a0 = refs[j * 3 + 0], a1 = refs[j * 3 + 1], a2 = refs[j * 3 + 2];
    const float b0 = refs[j * 3 + 3], b1 = refs[j * 3 + 4], b2 = refs[j * 3 + 5];
    lxy[i] = make_float4(-2.0f * a0, -2.0f * b0, -2.0f * a1, -2.0f * b1);
    lzw[i] = make_float4(-2.0f * a2, -2.0f * b2,
                         a0 * a0 + a1 * a1 + a2 * a2,
                         b0 * b0 + b1 * b1 + b2 * b2);
  }

  // Load queries while staging is in flight.
  f2 px2[KPT], py2[KPT], pz2[KPT];
  float m[KPT];
  const int p0 = blockIdx.x * PTS_PER_BLOCK + tid;
#pragma unroll
  for (int k = 0; k < KPT; k++) {
    const int p = p0 + k * TPB;
    const float qx = pts[p * 3 + 0];
    const float qy = pts[p * 3 + 1];
    const float qz = pts[p * 3 + 2];
    px2[k] = (f2){qx, qx};
    py2[k] = (f2){qy, qy};
    pz2[k] = (f2){qz, qz};
    m[k] = 1e30f;
  }
  __syncthreads();

  // min over chunk of (|y|^2 - 2 x.y), two refs per iteration via packed fma.
#pragma unroll 4
  for (int jp = 0; jp < MC / 2; jp++) {
    const float4 wxy = lxy[jp];
    const float4 wzw = lzw[jp];
    const f2 xp = (f2){wxy.x, wxy.y};
    const f2 yp = (f2){wxy.z, wxy.w};
    const f2 zp = (f2){wzw.x, wzw.y};
    const f2 wp = (f2){wzw.z, wzw.w};
#pragma unroll
    for (int k = 0; k < KPT; k++) {
      f2 s = pk_fma(pz2[k], zp, wp);
      s = pk_fma(py2[k], yp, s);
      s = pk_fma(px2[k], xp, s);
      m[k] = fminf(m[k], fminf(s.x, s.y));   // -> v_min3_f32
    }
  }

#pragma unroll
  for (int k = 0; k < KPT; k++) {
    const int p = p0 + k * TPB;
    const float qx = px2[k].x, qy = py2[k].x, qz = pz2[k].x;
    const float pn = qx * qx + qy * qy + qz * qz;
    partial[(c * (2 * BB) + zb) * NN + p] = m[k] + pn;
  }
}

// Min across chunks, block-sum, 1 atomic per block into out (zeroed by
// chamfer_partial upstream).  Block 0 also adds L_reg.
__global__ __launch_bounds__(256) void chamfer_reduce(
    const float* __restrict__ partial,
    const float* __restrict__ R, const float* __restrict__ S,
    const float* __restrict__ t, const float* __restrict__ Rgt,
    const float* __restrict__ Sgt, const float* __restrict__ tgt,
    float* __restrict__ out) {
  const int tid = threadIdx.x;
  const int q0 = blockIdx.x * 1024 + tid;   // 64 blocks cover NPTS
  float s = 0.0f;
#pragma unroll
  for (int kk = 0; kk < 4; kk++) {
    const int q = q0 + kk * 256;
    float m = 1e30f;
#pragma unroll
    for (int c = 0; c < NCHUNK; c++)
      m = fminf(m, partial[c * NPTS + q]);
    s += m;
  }
  for (int o = 32; o > 0; o >>= 1) s += __shfl_down(s, o);
  __shared__ float wsum[4];
  if ((tid & 63) == 0) wsum[tid >> 6] = s;
  __syncthreads();
  if (tid == 0) {
    const float bs = wsum[0] + wsum[1] + wsum[2] + wsum[3];
    atomicAdd(out, bs * (1.0f / (float)(BB * NN)));
  }

  if (blockIdx.x == 0) {
    float v = 0.0f;
    if (tid < 72) {                       // R @ R_gt^T - I, squared
      const int b = tid / 9, ik = tid % 9, i = ik / 3, k = ik % 3;
      const float* Rb = R + b * 9;
      const float* Gb = Rgt + b * 9;
      float d = Rb[i * 3 + 0] * Gb[k * 3 + 0] +
                Rb[i * 3 + 1] * Gb[k * 3 + 1] +
                Rb[i * 3 + 2] * Gb[k * 3 + 2];
      d -= (i == k) ? 1.0f : 0.0f;
      v = d * d;
    } else if (tid < 96) {                // (S - S_gt)^2
      const int i = tid - 72;
      const float d = S[i] - Sgt[i];
      v = d * d;
    } else if (tid < 120) {               // (t - t_gt)^2
      const int i = tid - 96;
      const float d = t[i] - tgt[i];
      v = d * d;
    }
    for (int o = 32; o > 0; o >>= 1) v += __shfl_down(v, o);
    __shared__ float rsum[4];
    if ((tid & 63) == 0) rsum[tid >> 6] = v;
    __syncthreads();
    if (tid == 0) atomicAdd(out, rsum[0] + rsum[1] + rsum[2] + rsum[3]);
  }
}

extern "C" void kernel_launch(void* const* d_in, const int* in_sizes, int n_in,
                              void* d_out, int out_size, void* d_ws, size_t ws_size,
                              hipStream_t stream) {
  const float* X   = (const float*)d_in[0];
  const float* Y   = (const float*)d_in[1];
  const float* R   = (const float*)d_in[2];
  const float* S   = (const float*)d_in[3];
  const float* t   = (const float*)d_in[4];
  const float* Rgt = (const float*)d_in[5];
  const float* Sgt = (const float*)d_in[6];
  const float* tgt = (const float*)d_in[7];

  float* partial = (float*)d_ws;
  float* out     = (float*)d_out;

  dim3 gA(NN / PTS_PER_BLOCK, NCHUNK, 2 * BB);   // (4, 16, 16) = 1024 blocks, 4/CU
  chamfer_partial<<<gA, TPB, 0, stream>>>(X, Y, partial, out);

  chamfer_reduce<<<NPTS / 1024, 256, 0, stream>>>(partial, R, S, t, Rgt, Sgt, tgt, out);
}

// Round 5
// 101.087 us; speedup vs baseline: 1.0830x; 1.0830x over previous
//
#include <hip/hip_runtime.h>

// HEGN loss: L_reg + bidirectional chamfer(x, y).  B=8, N=M=4096.
#define BB 8
#define NN 4096
#define MC 128                    // reference points staged per chunk
#define NCHUNK (NN / MC)          // 32
#define KPT 16                    // query points per thread
#define TPB 128                   // two waves per block
#define PTS_PER_BLOCK (TPB * KPT) // 2048
#define NPTS (2 * BB * NN)        // 65536 (both directions)

// ws layout: partial[c][zb][p]  c in [0,32), zb in [0,16), p in [0,4096) -> 8 MB

typedef __attribute__((ext_vector_type(2))) float f2;

__device__ __forceinline__ f2 pk_fma(f2 a, f2 b, f2 c) {
  f2 d;
  asm("v_pk_fma_f32 %0, %1, %2, %3" : "=v"(d) : "v"(a), "v"(b), "v"(c));
  return d;
}

__global__ __launch_bounds__(TPB) void chamfer_partial(
    const float* __restrict__ X, const float* __restrict__ Y,
    float* __restrict__ partial, float* __restrict__ out) {
  // Pair-packed staging: lxy[jp]=(-2x0,-2x1,-2y0,-2y1), lzw[jp]=(-2z0,-2z1,|r0|^2,|r1|^2)
  __shared__ float4 lxy[MC / 2];
  __shared__ float4 lzw[MC / 2];
  const int tid = threadIdx.x;
  const int zb  = blockIdx.z;     // (dir<<3) | b
  const int b   = zb & (BB - 1);
  const int dir = zb >> 3;
  const float* pts  = dir ? (Y + b * NN * 3) : (X + b * NN * 3);
  const float* refs = dir ? (X + b * NN * 3) : (Y + b * NN * 3);
  const int c = blockIdx.y;

  // Zero the output once; stream order guarantees this lands before
  // chamfer_reduce's atomics.
  if (blockIdx.x == 0 && blockIdx.y == 0 && blockIdx.z == 0 && tid == 0)
    out[0] = 0.0f;

  if (tid < MC / 2) {
    const int j = c * MC + 2 * tid;
    const float a0 = refs[j * 3 + 0], a1 = refs[j * 3 + 1], a2 = refs[j * 3 + 2];
    const float b0 = refs[j * 3 + 3], b1 = refs[j * 3 + 4], b2 = refs[j * 3 + 5];
    lxy[tid] = make_float4(-2.0f * a0, -2.0f * b0, -2.0f * a1, -2.0f * b1);
    lzw[tid] = make_float4(-2.0f * a2, -2.0f * b2,
                           a0 * a0 + a1 * a1 + a2 * a2,
                           b0 * b0 + b1 * b1 + b2 * b2);
  }

  // Load queries while staging is in flight.
  f2 px2[KPT], py2[KPT], pz2[KPT];
  float m[KPT];
  const int p0 = blockIdx.x * PTS_PER_BLOCK + tid;
#pragma unroll
  for (int k = 0; k < KPT; k++) {
    const int p = p0 + k * TPB;
    const float qx = pts[p * 3 + 0];
    const float qy = pts[p * 3 + 1];
    const float qz = pts[p * 3 + 2];
    px2[k] = (f2){qx, qx};
    py2[k] = (f2){qy, qy};
    pz2[k] = (f2){qz, qz};
    m[k] = 1e30f;
  }
  __syncthreads();

  // min over chunk of (|y|^2 - 2 x.y), two refs per iteration via packed fma.
#pragma unroll 2
  for (int jp = 0; jp < MC / 2; jp++) {
    const float4 wxy = lxy[jp];
    const float4 wzw = lzw[jp];
    const f2 xp = (f2){wxy.x, wxy.y};
    const f2 yp = (f2){wxy.z, wxy.w};
    const f2 zp = (f2){wzw.x, wzw.y};
    const f2 wp = (f2){wzw.z, wzw.w};
#pragma unroll
    for (int k = 0; k < KPT; k++) {
      f2 s = pk_fma(pz2[k], zp, wp);
      s = pk_fma(py2[k], yp, s);
      s = pk_fma(px2[k], xp, s);
      m[k] = fminf(m[k], fminf(s.x, s.y));   // -> v_min3_f32
    }
  }

#pragma unroll
  for (int k = 0; k < KPT; k++) {
    const int p = p0 + k * TPB;
    const float qx = px2[k].x, qy = py2[k].x, qz = pz2[k].x;
    const float pn = qx * qx + qy * qy + qz * qz;
    partial[(c * (2 * BB) + zb) * NN + p] = m[k] + pn;
  }
}

// Min across chunks, block-sum, 1 atomic per block into out (zeroed by
// chamfer_partial upstream).  Block 0 also adds L_reg.
__global__ __launch_bounds__(256) void chamfer_reduce(
    const float* __restrict__ partial,
    const float* __restrict__ R, const float* __restrict__ S,
    const float* __restrict__ t, const float* __restrict__ Rgt,
    const float* __restrict__ Sgt, const float* __restrict__ tgt,
    float* __restrict__ out) {
  const int tid = threadIdx.x;
  const int q0 = blockIdx.x * 1024 + tid;   // 64 blocks cover NPTS
  float s = 0.0f;
#pragma unroll
  for (int kk = 0; kk < 4; kk++) {
    const int q = q0 + kk * 256;
    float m = 1e30f;
#pragma unroll
    for (int c = 0; c < NCHUNK; c++)
      m = fminf(m, partial[c * NPTS + q]);
    s += m;
  }
  for (int o = 32; o > 0; o >>= 1) s += __shfl_down(s, o);
  __shared__ float wsum[4];
  if ((tid & 63) == 0) wsum[tid >> 6] = s;
  __syncthreads();
  if (tid == 0) {
    const float bs = wsum[0] + wsum[1] + wsum[2] + wsum[3];
    atomicAdd(out, bs * (1.0f / (float)(BB * NN)));
  }

  if (blockIdx.x == 0) {
    float v = 0.0f;
    if (tid < 72) {                       // R @ R_gt^T - I, squared
      const int b = tid / 9, ik = tid % 9, i = ik / 3, k = ik % 3;
      const float* Rb = R + b * 9;
      const float* Gb = Rgt + b * 9;
      float d = Rb[i * 3 + 0] * Gb[k * 3 + 0] +
                Rb[i * 3 + 1] * Gb[k * 3 + 1] +
                Rb[i * 3 + 2] * Gb[k * 3 + 2];
      d -= (i == k) ? 1.0f : 0.0f;
      v = d * d;
    } else if (tid < 96) {                // (S - S_gt)^2
      const int i = tid - 72;
      const float d = S[i] - Sgt[i];
      v = d * d;
    } else if (tid < 120) {               // (t - t_gt)^2
      const int i = tid - 96;
      const float d = t[i] - tgt[i];
      v = d * d;
    }
    for (int o = 32; o > 0; o >>= 1) v += __shfl_down(v, o);
    __shared__ float rsum[4];
    if ((tid & 63) == 0) rsum[tid >> 6] = v;
    __syncthreads();
    if (tid == 0) atomicAdd(out, rsum[0] + rsum[1] + rsum[2] + rsum[3]);
  }
}

extern "C" void kernel_launch(void* const* d_in, const int* in_sizes, int n_in,
                              void* d_out, int out_size, void* d_ws, size_t ws_size,
                              hipStream_t stream) {
  const float* X   = (const float*)d_in[0];
  const float* Y   = (const float*)d_in[1];
  const float* R   = (const float*)d_in[2];
  const float* S   = (const float*)d_in[3];
  const float* t   = (const float*)d_in[4];
  const float* Rgt = (const float*)d_in[5];
  const float* Sgt = (const float*)d_in[6];
  const float* tgt = (const float*)d_in[7];

  float* partial = (float*)d_ws;
  float* out     = (float*)d_out;

  dim3 gA(NN / PTS_PER_BLOCK, NCHUNK, 2 * BB);   // (2, 32, 16) = 1024 blocks, 2 waves/SIMD
  chamfer_partial<<<gA, TPB, 0, stream>>>(X, Y, partial, out);

  chamfer_reduce<<<NPTS / 1024, 256, 0, stream>>>(partial, R, S, t, Rgt, Sgt, tgt, out);
}

// Round 6
// 99.147 us; speedup vs baseline: 1.1042x; 1.0196x over previous
//
#include <hip/hip_runtime.h>

// HEGN loss: L_reg + bidirectional chamfer(x, y).  B=8, N=M=4096.
#define BB 8
#define NN 4096
#define MC 64                     // reference points staged per chunk
#define NCHUNK (NN / MC)          // 64
#define KPT 16                    // query points per thread
#define TPB 128                   // two waves per block
#define PTS_PER_BLOCK (TPB * KPT) // 2048
#define NPTS (2 * BB * NN)        // 65536 (both directions)

// ws layout: nnmin[zb][p] as uint-ordered floats, 65536 entries = 256 KB.
// Initialized to 0x7F7F7F7F (3.39e38) by hipMemsetAsync; atomicMin on the
// uint bit pattern == fmin for non-negative floats (d2 clamped >= 0).

typedef __attribute__((ext_vector_type(2))) float f2;

__device__ __forceinline__ f2 pk_fma(f2 a, f2 b, f2 c) {
  f2 d;
  asm("v_pk_fma_f32 %0, %1, %2, %3" : "=v"(d) : "v"(a), "v"(b), "v"(c));
  return d;
}

__global__ __launch_bounds__(TPB) void chamfer_partial(
    const float* __restrict__ X, const float* __restrict__ Y,
    unsigned int* __restrict__ nnmin, float* __restrict__ out) {
  // Pair-packed staging: lxy[jp]=(-2x0,-2x1,-2y0,-2y1), lzw[jp]=(-2z0,-2z1,|r0|^2,|r1|^2)
  __shared__ float4 lxy[MC / 2];
  __shared__ float4 lzw[MC / 2];
  const int tid = threadIdx.x;
  const int zb  = blockIdx.z;     // (dir<<3) | b
  const int b   = zb & (BB - 1);
  const int dir = zb >> 3;
  const float* pts  = dir ? (Y + b * NN * 3) : (X + b * NN * 3);
  const float* refs = dir ? (X + b * NN * 3) : (Y + b * NN * 3);
  const int c = blockIdx.y;

  // Zero the output once; stream order guarantees this lands before
  // chamfer_reduce's atomics.
  if (blockIdx.x == 0 && blockIdx.y == 0 && blockIdx.z == 0 && tid == 0)
    out[0] = 0.0f;

  if (tid < MC / 2) {
    const int j = c * MC + 2 * tid;
    const float a0 = refs[j * 3 + 0], a1 = refs[j * 3 + 1], a2 = refs[j * 3 + 2];
    const float b0 = refs[j * 3 + 3], b1 = refs[j * 3 + 4], b2 = refs[j * 3 + 5];
    lxy[tid] = make_float4(-2.0f * a0, -2.0f * b0, -2.0f * a1, -2.0f * b1);
    lzw[tid] = make_float4(-2.0f * a2, -2.0f * b2,
                           a0 * a0 + a1 * a1 + a2 * a2,
                           b0 * b0 + b1 * b1 + b2 * b2);
  }

  // Load queries while staging is in flight.
  f2 px2[KPT], py2[KPT], pz2[KPT];
  float m[KPT];
  const int p0 = blockIdx.x * PTS_PER_BLOCK + tid;
#pragma unroll
  for (int k = 0; k < KPT; k++) {
    const int p = p0 + k * TPB;
    const float qx = pts[p * 3 + 0];
    const float qy = pts[p * 3 + 1];
    const float qz = pts[p * 3 + 2];
    px2[k] = (f2){qx, qx};
    py2[k] = (f2){qy, qy};
    pz2[k] = (f2){qz, qz};
    m[k] = 1e30f;
  }
  __syncthreads();

  // min over chunk of (|y|^2 - 2 x.y), two refs per iteration via packed fma.
#pragma unroll 2
  for (int jp = 0; jp < MC / 2; jp++) {
    const float4 wxy = lxy[jp];
    const float4 wzw = lzw[jp];
    const f2 xp = (f2){wxy.x, wxy.y};
    const f2 yp = (f2){wxy.z, wxy.w};
    const f2 zp = (f2){wzw.x, wzw.y};
    const f2 wp = (f2){wzw.z, wzw.w};
#pragma unroll
    for (int k = 0; k < KPT; k++) {
      f2 s = pk_fma(pz2[k], zp, wp);
      s = pk_fma(py2[k], yp, s);
      s = pk_fma(px2[k], xp, s);
      m[k] = fminf(m[k], fminf(s.x, s.y));   // -> v_min3_f32
    }
  }

#pragma unroll
  for (int k = 0; k < KPT; k++) {
    const int p = p0 + k * TPB;
    const float qx = px2[k].x, qy = py2[k].x, qz = pz2[k].x;
    const float pn = qx * qx + qy * qy + qz * qz;
    const float d2 = fmaxf(m[k] + pn, 0.0f);  // clamp: keeps uint-order == float-order
    atomicMin(&nnmin[zb * NN + p], __float_as_uint(d2));
  }
}

// Sum the 64K per-point NN mins (256 KB), 1 atomic per block into out
// (zeroed by chamfer_partial upstream).  Block 0 also adds L_reg.
__global__ __launch_bounds__(256) void chamfer_reduce(
    const float* __restrict__ nnmin,
    const float* __restrict__ R, const float* __restrict__ S,
    const float* __restrict__ t, const float* __restrict__ Rgt,
    const float* __restrict__ Sgt, const float* __restrict__ tgt,
    float* __restrict__ out) {
  const int tid = threadIdx.x;
  const int base = blockIdx.x * 2048;        // 32 blocks cover NPTS
  const float4* v = (const float4*)nnmin;
  const float4 a0 = v[(base >> 2) + tid];
  const float4 a1 = v[(base >> 2) + 256 + tid];
  float s = (a0.x + a0.y) + (a0.z + a0.w) + (a1.x + a1.y) + (a1.z + a1.w);
  for (int o = 32; o > 0; o >>= 1) s += __shfl_down(s, o);
  __shared__ float wsum[4];
  if ((tid & 63) == 0) wsum[tid >> 6] = s;
  __syncthreads();
  if (tid == 0) {
    const float bs = wsum[0] + wsum[1] + wsum[2] + wsum[3];
    atomicAdd(out, bs * (1.0f / (float)(BB * NN)));
  }

  if (blockIdx.x == 0) {
    float v2 = 0.0f;
    if (tid < 72) {                       // R @ R_gt^T - I, squared
      const int b = tid / 9, ik = tid % 9, i = ik / 3, k = ik % 3;
      const float* Rb = R + b * 9;
      const float* Gb = Rgt + b * 9;
      float d = Rb[i * 3 + 0] * Gb[k * 3 + 0] +
                Rb[i * 3 + 1] * Gb[k * 3 + 1] +
                Rb[i * 3 + 2] * Gb[k * 3 + 2];
      d -= (i == k) ? 1.0f : 0.0f;
      v2 = d * d;
    } else if (tid < 96) {                // (S - S_gt)^2
      const int i = tid - 72;
      const float d = S[i] - Sgt[i];
      v2 = d * d;
    } else if (tid < 120) {               // (t - t_gt)^2
      const int i = tid - 96;
      const float d = t[i] - tgt[i];
      v2 = d * d;
    }
    for (int o = 32; o > 0; o >>= 1) v2 += __shfl_down(v2, o);
    __shared__ float rsum[4];
    if ((tid & 63) == 0) rsum[tid >> 6] = v2;
    __syncthreads();
    if (tid == 0) atomicAdd(out, rsum[0] + rsum[1] + rsum[2] + rsum[3]);
  }
}

extern "C" void kernel_launch(void* const* d_in, const int* in_sizes, int n_in,
                              void* d_out, int out_size, void* d_ws, size_t ws_size,
                              hipStream_t stream) {
  const float* X   = (const float*)d_in[0];
  const float* Y   = (const float*)d_in[1];
  const float* R   = (const float*)d_in[2];
  const float* S   = (const float*)d_in[3];
  const float* t   = (const float*)d_in[4];
  const float* Rgt = (const float*)d_in[5];
  const float* Sgt = (const float*)d_in[6];
  const float* tgt = (const float*)d_in[7];

  unsigned int* nnmin = (unsigned int*)d_ws;
  float* out = (float*)d_out;

  // 0x7F7F7F7F == 3.39e38f: valid "+inf-like" init for uint-ordered fmin.
  hipMemsetAsync(nnmin, 0x7F, NPTS * sizeof(unsigned int), stream);

  dim3 gA(NN / PTS_PER_BLOCK, NCHUNK, 2 * BB);   // (2, 64, 16) = 2048 blocks, 4 waves/SIMD
  chamfer_partial<<<gA, TPB, 0, stream>>>(X, Y, nnmin, out);

  chamfer_reduce<<<NPTS / 2048, 256, 0, stream>>>((const float*)nnmin,
                                                  R, S, t, Rgt, Sgt, tgt, out);
}